// Round 7
// baseline (846.822 us; speedup 1.0000x reference)
//
#include <hip/hip_runtime.h>
#include <math.h>

#define T_LEN   1024
#define S_SEAS  168
#define H_SZ    128
#define G_SZ    512   // 4*H
#define WIN_SZ  168
#define OUT_SZ  24
#define N_WIN   833
#define BB      16
#define NBLK    ((N_WIN + BB - 1) / BB)   // 53
#define NPAD    (NBLK * BB)               // 848

typedef __attribute__((ext_vector_type(8))) __bf16 bf16x8;
typedef __attribute__((ext_vector_type(4))) float  f32x4;

__device__ __forceinline__ float fsig(float x) {
    return __fdividef(1.0f, 1.0f + __expf(-x));
}
__device__ __forceinline__ float ftanh(float x) {
    return 1.0f - __fdividef(2.0f, __expf(2.0f * x) + 1.0f);
}

// ---------------------------------------------------------------------------
// Kernel 1: es_scan (block 0) + weight prep (blocks 1..160) — independent
// work merged into one launch; prep runs concurrently with the serial scan.
// ---------------------------------------------------------------------------
__global__ __launch_bounds__(256) void pre_kernel(
    const float* __restrict__ x,
    const float* __restrict__ lvl_raw,
    const float* __restrict__ seas_raw,
    const float* __restrict__ seas_params,
    const float* __restrict__ Wh0,
    const float* __restrict__ Wx1,
    const float* __restrict__ Wh1,
    const float* __restrict__ tanhW,
    float* __restrict__ levels,
    float* __restrict__ wsv,
    uint4* __restrict__ pw0,
    uint4* __restrict__ pw1,
    float* __restrict__ tanhWT) {
    __shared__ float xl[T_LEN];
    __shared__ float buf[S_SEAS];
    const int t = threadIdx.x;

    if (blockIdx.x == 0) {
        // ------- Holt-Winters ES scan (serial, software-pipelined) -------
        for (int i = t; i < T_LEN; i += 256) xl[i] = x[i];
        for (int i = t; i < S_SEAS; i += 256) {
            const float w = expf(seas_params[i]);
            buf[i] = w;
            wsv[i] = w;
        }
        __syncthreads();
        if (t == 0) {
            const float a  = 1.0f / (1.0f + expf(-lvl_raw[0]));
            const float g  = 1.0f / (1.0f + expf(-seas_raw[0]));
            const float ca = 1.0f - a, cg = 1.0f - g;
            float level = __fdividef(xl[0], buf[0]);
            levels[0] = level;
            wsv[S_SEAS] = buf[0];   // ws_full[168] = w_init[0]

            float wq[8], tq[8];
#pragma unroll
            for (int k = 0; k < 8; ++k) {
                const int i = 1 + k;
                const float w = buf[i % S_SEAS];
                wq[k] = w;
                tq[k] = __fdividef(a * xl[i], w);
            }
            for (int i = 1; i < T_LEN; i += 8) {
#pragma unroll
                for (int s = 0; s < 8; ++s) {
                    const int ii = i + s;
                    if (ii >= T_LEN) break;
                    const float w  = wq[s];
                    const float nl = tq[s] + ca * level;   // chain: 1 FMA
                    const float nw = cg * w + __fdividef(g * xl[ii], nl);
                    levels[ii] = nl;
                    buf[ii % S_SEAS] = nw;
                    if (ii + S_SEAS < T_LEN) wsv[ii + S_SEAS] = nw;
                    level = nl;
                    const int i8 = ii + 8;
                    if (i8 < T_LEN) {
                        const float w8 = buf[i8 % S_SEAS];
                        wq[s] = w8;
                        tq[s] = __fdividef(a * xl[i8], w8);
                    }
                }
            }
        }
        return;
    }

    // ------- weight prep: pack MFMA B-frags (m92/m97 layout) -------
    const int idx = (blockIdx.x - 1) * 256 + t;
    auto bfr = [](float f) -> unsigned int {   // fp32 -> bf16 (RNE)
        union { float f; unsigned int u; } v; v.f = f;
        return ((v.u + 0x7FFFu + ((v.u >> 16) & 1u)) >> 16) & 0xFFFFu;
    };
    if (idx < 8192) {                       // pw0: Wh0, 128 frags (8w x 4ns x 4kt)
        const int l = idx & 63, f = idx >> 6;
        const int kt = f & 3, ns = (f >> 2) & 3, w = f >> 4;
        const int g = ns * 128 + w * 16 + (l & 15);
        const int kb = kt * 32 + (l >> 4) * 8;
        const float* s = Wh0 + g * H_SZ + kb;
        uint4 o;
        unsigned int* po = &o.x;
        for (int p = 0; p < 4; ++p) po[p] = bfr(s[2 * p]) | (bfr(s[2 * p + 1]) << 16);
        pw0[idx] = o;
    } else if (idx < 8192 + 16384) {        // pw1: [Wx1 (kt<4); Wh1 (kt>=4)]
        const int j = idx - 8192;
        const int l = j & 63, f = j >> 6;
        const int kt = f & 7, ns = (f >> 3) & 3, w = f >> 5;
        const int g = ns * 128 + w * 16 + (l & 15);
        const float* srcm = (kt < 4) ? Wx1 : Wh1;
        const int kb = (kt & 3) * 32 + (l >> 4) * 8;
        const float* s = srcm + g * H_SZ + kb;
        uint4 o;
        unsigned int* po = &o.x;
        for (int p = 0; p < 4; ++p) po[p] = bfr(s[2 * p]) | (bfr(s[2 * p + 1]) << 16);
        pw1[j] = o;
    } else if (idx < 8192 + 16384 + 16384) {  // tanh_W transpose (fp32)
        const int j = idx - 8192 - 16384;
        const int m = j >> 7, k = j & 127;
        tanhWT[k * H_SZ + m] = tanhW[j];
    }
}

// ---------------------------------------------------------------------------
// Kernel 2: layer-0 LSTM. Wh0 in AGPRs; windowing (log-deseasonalize) fused
// into the staging phase; hs0 stores issued at the TOP of the next step so
// the pre-barrier vmcnt drain is covered by a full step of compute.
// Unroll-2: LDS addresses loop-invariant, buffer parity literal.
// ---------------------------------------------------------------------------
__global__ __launch_bounds__(512, 2) void l0_kernel(
    const float* __restrict__ x,
    const float* __restrict__ levels,
    const float* __restrict__ wsv,
    const float* __restrict__ noise_in,
    const float* __restrict__ Wx0,
    const float* __restrict__ b0v,
    const uint4* __restrict__ pw0,
    __bf16* __restrict__ hs0) {
    __shared__ __bf16 h0s[2][16 * 128];    // 8KB, swizzled, pitch 256B
    __shared__ float  xls[WIN_SZ][16];     // 10.75KB

    const int tid  = threadIdx.x;
    const int w    = tid >> 6;
    const int lane = tid & 63;
    const int cc   = lane & 15;
    const int kl   = lane >> 4;
    const int base = blockIdx.x * BB;

    // staging: fused window computation (log deseasonalized + noise)
    for (int i = tid; i < WIN_SZ * BB; i += 512) {
        const int t = i >> 4, m = i & 15;
        const int nn = base + m;
        float v = 0.0f;
        if (nn < N_WIN) {
            const float lev = levels[nn + WIN_SZ];
            const int tt = nn + t;
            v = logf(x[tt] / (lev * wsv[tt])) + noise_in[nn * WIN_SZ + t];
        }
        xls[t][m] = v;
    }
    for (int i = tid; i < 2 * 16 * 128; i += 512) (&h0s[0][0])[i] = (__bf16)0.0f;

    // Wh0 frags -> AGPRs (proven round 6)
    const bf16x8* p0 = (const bf16x8*)pw0;
    bf16x8 wB0[4][4];
#pragma unroll
    for (int ns = 0; ns < 4; ++ns)
#pragma unroll
        for (int kt = 0; kt < 4; ++kt)
            wB0[ns][kt] = p0[((w * 4 + ns) * 4 + kt) * 64 + lane];
#pragma unroll
    for (int ns = 0; ns < 4; ++ns)
#pragma unroll
        for (int kt = 0; kt < 4; ++kt)
            asm("" : "+a"(wB0[ns][kt]));

    float b0r[4], wx0r[4];
#pragma unroll
    for (int ns = 0; ns < 4; ++ns) {
        const int g = ns * 128 + w * 16 + cc;
        b0r[ns]  = b0v[g];
        wx0r[ns] = Wx0[g];
    }
    float c0r[4] = {0.f, 0.f, 0.f, 0.f};

    // loop-invariant swizzled LDS addresses (byte offsets)
    int rdA[4], wrA[4], goff[4];
#pragma unroll
    for (int kt = 0; kt < 4; ++kt)
        rdA[kt] = cc * 256 + ((kt * 64 + kl * 16) ^ ((cc & 7) << 4));
#pragma unroll
    for (int r = 0; r < 4; ++r) {
        const int row = kl * 4 + r;
        wrA[r]  = row * 256 + (((w * 16 + cc) * 2) ^ ((row & 7) << 4));
        goff[r] = (base + row) * H_SZ + w * 16 + cc;
    }
    __bf16 hvs0 = (__bf16)0.f, hvs1 = (__bf16)0.f, hvs2 = (__bf16)0.f, hvs3 = (__bf16)0.f;
    __syncthreads();

    char* const hb0 = (char*)&h0s[0][0];

#define L0_STEP(T, P)                                                          \
    {                                                                          \
        const int t_ = (T);                                                    \
        if (t_ > 0) {  /* store h(t-1): drain covered by this whole step */    \
            const int off_ = (t_ - 1) * (NPAD * H_SZ);                         \
            hs0[off_ + goff[0]] = hvs0;                                        \
            hs0[off_ + goff[1]] = hvs1;                                        \
            hs0[off_ + goff[2]] = hvs2;                                        \
            hs0[off_ + goff[3]] = hvs3;                                        \
        }                                                                      \
        const float4 xt_ = *(const float4*)&xls[t_][kl * 4];                   \
        const float xa_[4] = {xt_.x, xt_.y, xt_.z, xt_.w};                     \
        f32x4 a0_, a1_, a2_, a3_;                                              \
        _Pragma("unroll")                                                      \
        for (int r = 0; r < 4; ++r) {                                          \
            a0_[r] = b0r[0] + wx0r[0] * xa_[r];                                \
            a1_[r] = b0r[1] + wx0r[1] * xa_[r];                                \
            a2_[r] = b0r[2] + wx0r[2] * xa_[r];                                \
            a3_[r] = b0r[3] + wx0r[3] * xa_[r];                                \
        }                                                                      \
        _Pragma("unroll")                                                      \
        for (int kt = 0; kt < 4; ++kt) {                                       \
            const bf16x8 af_ = *(const bf16x8*)(hb0 + (P) * 4096 + rdA[kt]);   \
            a0_ = __builtin_amdgcn_mfma_f32_16x16x32_bf16(af_, wB0[0][kt], a0_, 0, 0, 0); \
            a1_ = __builtin_amdgcn_mfma_f32_16x16x32_bf16(af_, wB0[1][kt], a1_, 0, 0, 0); \
            a2_ = __builtin_amdgcn_mfma_f32_16x16x32_bf16(af_, wB0[2][kt], a2_, 0, 0, 0); \
            a3_ = __builtin_amdgcn_mfma_f32_16x16x32_bf16(af_, wB0[3][kt], a3_, 0, 0, 0); \
        }                                                                      \
        _Pragma("unroll")                                                      \
        for (int r = 0; r < 4; ++r) {                                          \
            const float ig_ = fsig(a0_[r]);                                    \
            const float fg_ = fsig(a1_[r]);                                    \
            const float gg_ = ftanh(a2_[r]);                                   \
            const float og_ = fsig(a3_[r]);                                    \
            const float c_  = fg_ * c0r[r] + ig_ * gg_;                        \
            c0r[r] = c_;                                                       \
            const __bf16 hb_ = (__bf16)(og_ * ftanh(c_));                      \
            *(__bf16*)(hb0 + (((P) ^ 1) * 4096) + wrA[r]) = hb_;               \
            if (r == 0) hvs0 = hb_;                                            \
            if (r == 1) hvs1 = hb_;                                            \
            if (r == 2) hvs2 = hb_;                                            \
            if (r == 3) hvs3 = hb_;                                            \
        }                                                                      \
        __syncthreads();                                                       \
    }

    for (int tp = 0; tp < WIN_SZ / 2; ++tp) {
        L0_STEP(2 * tp, 0)
        L0_STEP(2 * tp + 1, 1)
    }
#undef L0_STEP
    // epilogue: store h(167)
    {
        const int off_ = (WIN_SZ - 1) * (NPAD * H_SZ);
        hs0[off_ + goff[0]] = hvs0;
        hs0[off_ + goff[1]] = hvs1;
        hs0[off_ + goff[2]] = hvs2;
        hs0[off_ + goff[3]] = hvs3;
    }
}

// ---------------------------------------------------------------------------
// Kernel 3: layer-1 LSTM + head + labels. Wx1+Wh1 in AGPRs; hs0 A-frags
// prefetched one step ahead into alternating named reg sets (no copies);
// Wx/Wh accumulate into SEPARATE accs (4-deep chains in parallel, not 8).
// Epilogue: block-local tanh-dense + linear head, labels, loss scalar.
// ---------------------------------------------------------------------------
__global__ __launch_bounds__(512, 2) void l1_kernel(
    const __bf16* __restrict__ hs0,
    const float* __restrict__ b1v,
    const uint4* __restrict__ pw1,
    const float* __restrict__ tanhWT,
    const float* __restrict__ tanhB,
    const float* __restrict__ linW,
    const float* __restrict__ linB,
    const float* __restrict__ x,
    const float* __restrict__ levels,
    const float* __restrict__ wsv,
    const float* __restrict__ noise_lab,
    float* __restrict__ out) {
    __shared__ __bf16 h1s[2][16 * 128];    // 8KB, swizzled
    __shared__ float  hfl[16][129];        // final h (f32) for head
    __shared__ float  featl[16][128];      // tanh features

    const int tid  = threadIdx.x;
    const int w    = tid >> 6;
    const int lane = tid & 63;
    const int cc   = lane & 15;
    const int kl   = lane >> 4;
    const int base = blockIdx.x * BB;

    for (int i = tid; i < 2 * 16 * 128; i += 512) (&h1s[0][0])[i] = (__bf16)0.0f;

    // Wx1 (kt<4) + Wh1 (kt>=4) frags -> AGPRs
    const bf16x8* p1 = (const bf16x8*)pw1;
    bf16x8 wX[4][4], wH[4][4];
#pragma unroll
    for (int ns = 0; ns < 4; ++ns)
#pragma unroll
        for (int kt = 0; kt < 4; ++kt) {
            wX[ns][kt] = p1[((w * 4 + ns) * 8 + kt) * 64 + lane];
            wH[ns][kt] = p1[((w * 4 + ns) * 8 + kt + 4) * 64 + lane];
        }
#pragma unroll
    for (int ns = 0; ns < 4; ++ns)
#pragma unroll
        for (int kt = 0; kt < 4; ++kt) {
            asm("" : "+a"(wX[ns][kt]));
            asm("" : "+a"(wH[ns][kt]));
        }

    float b1r[4];
#pragma unroll
    for (int ns = 0; ns < 4; ++ns) b1r[ns] = b1v[ns * 128 + w * 16 + cc];
    float c1r[4] = {0.f, 0.f, 0.f, 0.f};

    int rdA[4], wrA[4];
#pragma unroll
    for (int kt = 0; kt < 4; ++kt)
        rdA[kt] = cc * 256 + ((kt * 64 + kl * 16) ^ ((cc & 7) << 4));
#pragma unroll
    for (int r = 0; r < 4; ++r) {
        const int row = kl * 4 + r;
        wrA[r] = row * 256 + (((w * 16 + cc) * 2) ^ ((row & 7) << 4));
    }

    // A-frag prefetch for t=0 (set A)
    const size_t arow = (size_t)(base + cc) * H_SZ + kl * 8;
    bf16x8 fA0 = *(const bf16x8*)&hs0[arow + 0];
    bf16x8 fA1 = *(const bf16x8*)&hs0[arow + 32];
    bf16x8 fA2 = *(const bf16x8*)&hs0[arow + 64];
    bf16x8 fA3 = *(const bf16x8*)&hs0[arow + 96];
    bf16x8 fB0, fB1, fB2, fB3;
    __syncthreads();

    char* const hb1 = (char*)&h1s[0][0];

#define L1_STEP(T, P, C0, C1, C2, C3, N0, N1, N2, N3)                          \
    {                                                                          \
        const int t_ = (T);                                                    \
        if (t_ + 1 < WIN_SZ) {  /* issue next prefetch first */                \
            const __bf16* p_ = hs0 + (size_t)(t_ + 1) * (NPAD * H_SZ) + arow;  \
            N0 = *(const bf16x8*)(p_);                                         \
            N1 = *(const bf16x8*)(p_ + 32);                                    \
            N2 = *(const bf16x8*)(p_ + 64);                                    \
            N3 = *(const bf16x8*)(p_ + 96);                                    \
        }                                                                      \
        f32x4 w0_ = {b1r[0], b1r[0], b1r[0], b1r[0]};                          \
        f32x4 w1_ = {b1r[1], b1r[1], b1r[1], b1r[1]};                          \
        f32x4 w2_ = {b1r[2], b1r[2], b1r[2], b1r[2]};                          \
        f32x4 w3_ = {b1r[3], b1r[3], b1r[3], b1r[3]};                          \
        f32x4 h0_ = {0.f, 0.f, 0.f, 0.f};                                      \
        f32x4 h1_ = {0.f, 0.f, 0.f, 0.f};                                      \
        f32x4 h2_ = {0.f, 0.f, 0.f, 0.f};                                      \
        f32x4 h3_ = {0.f, 0.f, 0.f, 0.f};                                      \
        w0_ = __builtin_amdgcn_mfma_f32_16x16x32_bf16(C0, wX[0][0], w0_, 0, 0, 0); \
        w1_ = __builtin_amdgcn_mfma_f32_16x16x32_bf16(C0, wX[1][0], w1_, 0, 0, 0); \
        w2_ = __builtin_amdgcn_mfma_f32_16x16x32_bf16(C0, wX[2][0], w2_, 0, 0, 0); \
        w3_ = __builtin_amdgcn_mfma_f32_16x16x32_bf16(C0, wX[3][0], w3_, 0, 0, 0); \
        w0_ = __builtin_amdgcn_mfma_f32_16x16x32_bf16(C1, wX[0][1], w0_, 0, 0, 0); \
        w1_ = __builtin_amdgcn_mfma_f32_16x16x32_bf16(C1, wX[1][1], w1_, 0, 0, 0); \
        w2_ = __builtin_amdgcn_mfma_f32_16x16x32_bf16(C1, wX[2][1], w2_, 0, 0, 0); \
        w3_ = __builtin_amdgcn_mfma_f32_16x16x32_bf16(C1, wX[3][1], w3_, 0, 0, 0); \
        w0_ = __builtin_amdgcn_mfma_f32_16x16x32_bf16(C2, wX[0][2], w0_, 0, 0, 0); \
        w1_ = __builtin_amdgcn_mfma_f32_16x16x32_bf16(C2, wX[1][2], w1_, 0, 0, 0); \
        w2_ = __builtin_amdgcn_mfma_f32_16x16x32_bf16(C2, wX[2][2], w2_, 0, 0, 0); \
        w3_ = __builtin_amdgcn_mfma_f32_16x16x32_bf16(C2, wX[3][2], w3_, 0, 0, 0); \
        w0_ = __builtin_amdgcn_mfma_f32_16x16x32_bf16(C3, wX[0][3], w0_, 0, 0, 0); \
        w1_ = __builtin_amdgcn_mfma_f32_16x16x32_bf16(C3, wX[1][3], w1_, 0, 0, 0); \
        w2_ = __builtin_amdgcn_mfma_f32_16x16x32_bf16(C3, wX[2][3], w2_, 0, 0, 0); \
        w3_ = __builtin_amdgcn_mfma_f32_16x16x32_bf16(C3, wX[3][3], w3_, 0, 0, 0); \
        _Pragma("unroll")                                                      \
        for (int kt = 0; kt < 4; ++kt) {                                       \
            const bf16x8 af_ = *(const bf16x8*)(hb1 + (P) * 4096 + rdA[kt]);   \
            h0_ = __builtin_amdgcn_mfma_f32_16x16x32_bf16(af_, wH[0][kt], h0_, 0, 0, 0); \
            h1_ = __builtin_amdgcn_mfma_f32_16x16x32_bf16(af_, wH[1][kt], h1_, 0, 0, 0); \
            h2_ = __builtin_amdgcn_mfma_f32_16x16x32_bf16(af_, wH[2][kt], h2_, 0, 0, 0); \
            h3_ = __builtin_amdgcn_mfma_f32_16x16x32_bf16(af_, wH[3][kt], h3_, 0, 0, 0); \
        }                                                                      \
        _Pragma("unroll")                                                      \
        for (int r = 0; r < 4; ++r) {                                          \
            const float ig_ = fsig(w0_[r] + h0_[r]);                           \
            const float fg_ = fsig(w1_[r] + h1_[r]);                           \
            const float gg_ = ftanh(w2_[r] + h2_[r]);                          \
            const float og_ = fsig(w3_[r] + h3_[r]);                           \
            const float c_  = fg_ * c1r[r] + ig_ * gg_;                        \
            c1r[r] = c_;                                                       \
            const float hv_ = og_ * ftanh(c_);                                 \
            if (t_ == WIN_SZ - 1) {                                            \
                hfl[kl * 4 + r][w * 16 + cc] = hv_;                            \
            } else {                                                           \
                *(__bf16*)(hb1 + (((P) ^ 1) * 4096) + wrA[r]) = (__bf16)hv_;   \
            }                                                                  \
        }                                                                      \
        __syncthreads();                                                       \
    }

    for (int tp = 0; tp < WIN_SZ / 2; ++tp) {
        L1_STEP(2 * tp, 0, fA0, fA1, fA2, fA3, fB0, fB1, fB2, fB3)
        L1_STEP(2 * tp + 1, 1, fB0, fB1, fB2, fB3, fA0, fA1, fA2, fA3)
    }
#undef L1_STEP

    // ---- epilogue: feat = tanh(h @ tanhW^T + tanhB) (block-local) ----
    for (int p = tid; p < BB * H_SZ; p += 512) {
        const int m = p >> 7, u = p & 127;
        float acc = tanhB[u];
        for (int k = 0; k < H_SZ; ++k)
            acc += hfl[m][k] * tanhWT[k * H_SZ + u];
        featl[m][u] = tanhf(acc);
    }
    __syncthreads();

    // ---- out = feat @ linW^T + linB; labels; loss scalar ----
    for (int p = tid; p < BB * OUT_SZ; p += 512) {
        const int m = p / OUT_SZ, o = p % OUT_SZ;
        const int nn = base + m;
        if (nn < N_WIN) {
            float acc = linB[o];
            for (int k = 0; k < H_SZ; ++k)
                acc += featl[m][k] * linW[o * H_SZ + k];
            out[nn * OUT_SZ + o] = acc;
            const float lev = levels[nn + WIN_SZ];
            const int tt = nn + WIN_SZ + o;
            out[N_WIN * OUT_SZ + nn * OUT_SZ + o] =
                logf(x[tt] / (lev * wsv[tt])) + noise_lab[nn * OUT_SZ + o];
        }
    }
    if (blockIdx.x == 0 && tid == 0)
        out[2 * N_WIN * OUT_SZ] = 0.0f;   // level_var_loss
}

// ---------------------------------------------------------------------------
extern "C" void kernel_launch(void* const* d_in, const int* in_sizes, int n_in,
                              void* d_out, int out_size, void* d_ws, size_t ws_size,
                              hipStream_t stream) {
    const float* x           = (const float*)d_in[0];
    const float* lvl_raw     = (const float*)d_in[1];
    const float* seas_raw    = (const float*)d_in[2];
    const float* seas_params = (const float*)d_in[3];
    const float* noise_in    = (const float*)d_in[4];
    const float* noise_lab   = (const float*)d_in[5];
    const float* Wx0         = (const float*)d_in[6];
    const float* Wh0         = (const float*)d_in[7];
    const float* b0v         = (const float*)d_in[8];
    const float* Wx1         = (const float*)d_in[9];
    const float* Wh1         = (const float*)d_in[10];
    const float* b1v         = (const float*)d_in[11];
    const float* tanhW       = (const float*)d_in[12];
    const float* tanhB       = (const float*)d_in[13];
    const float* linW        = (const float*)d_in[14];
    const float* linB        = (const float*)d_in[15];
    float* out = (float*)d_out;

    // workspace layout (floats; pw0/pw1/hs0 16B-aligned by construction)
    float* wsf    = (float*)d_ws;
    float* levels = wsf;                                   // 1024
    float* wsv    = levels + T_LEN;                        // 1024
    float* tanhWT = wsv + T_LEN;                           // 16384
    uint4* pw0    = (uint4*)(tanhWT + H_SZ * H_SZ);        // 8192 uint4
    uint4* pw1    = pw0 + 8192;                            // 16384 uint4
    __bf16* hs0   = (__bf16*)(pw1 + 16384);                // 168*848*128 bf16

    hipLaunchKernelGGL(pre_kernel, dim3(161), dim3(256), 0, stream,
                       x, lvl_raw, seas_raw, seas_params, Wh0, Wx1, Wh1, tanhW,
                       levels, wsv, pw0, pw1, tanhWT);
    hipLaunchKernelGGL(l0_kernel, dim3(NBLK), dim3(512), 0, stream,
                       x, levels, wsv, noise_in, Wx0, b0v, pw0, hs0);
    hipLaunchKernelGGL(l1_kernel, dim3(NBLK), dim3(512), 0, stream,
                       hs0, b1v, pw1, tanhWT, tanhB, linW, linB,
                       x, levels, wsv, noise_lab, out);
}

// Round 8
// 771.101 us; speedup vs baseline: 1.0982x; 1.0982x over previous
//
#include <hip/hip_runtime.h>
#include <math.h>

#define T_LEN   1024
#define S_SEAS  168
#define H_SZ    128
#define G_SZ    512   // 4*H
#define WIN_SZ  168
#define OUT_SZ  24
#define N_WIN   833
#define BB      16
#define NBLK    ((N_WIN + BB - 1) / BB)   // 53
#define NPAD    (NBLK * BB)               // 848

typedef __attribute__((ext_vector_type(8))) __bf16 bf16x8;
typedef __attribute__((ext_vector_type(4))) float  f32x4;

__device__ __forceinline__ float fsig(float x) {
    return __fdividef(1.0f, 1.0f + __expf(-x));
}
__device__ __forceinline__ float ftanh(float x) {
    return 1.0f - __fdividef(2.0f, __expf(2.0f * x) + 1.0f);
}

// Counted-wait barrier (T3/T4, m201-verified): order LDS only; leave global
// loads/stores in flight across the barrier (no vmcnt drain).
#define LDS_BARRIER()                                        \
    do {                                                     \
        asm volatile("s_waitcnt lgkmcnt(0)" ::: "memory");   \
        __builtin_amdgcn_s_barrier();                        \
    } while (0)

// ---------------------------------------------------------------------------
// Kernel 1: es_scan (block 0) + weight prep (blocks 1..160).
// ---------------------------------------------------------------------------
__global__ __launch_bounds__(256) void pre_kernel(
    const float* __restrict__ x,
    const float* __restrict__ lvl_raw,
    const float* __restrict__ seas_raw,
    const float* __restrict__ seas_params,
    const float* __restrict__ Wh0,
    const float* __restrict__ Wx1,
    const float* __restrict__ Wh1,
    const float* __restrict__ tanhW,
    float* __restrict__ levels,
    float* __restrict__ wsv,
    uint4* __restrict__ pw0,
    uint4* __restrict__ pw1,
    float* __restrict__ tanhWT) {
    __shared__ float xl[T_LEN];
    __shared__ float buf[S_SEAS];
    const int t = threadIdx.x;

    if (blockIdx.x == 0) {
        for (int i = t; i < T_LEN; i += 256) xl[i] = x[i];
        for (int i = t; i < S_SEAS; i += 256) {
            const float w = expf(seas_params[i]);
            buf[i] = w;
            wsv[i] = w;
        }
        __syncthreads();
        if (t == 0) {
            const float a  = 1.0f / (1.0f + expf(-lvl_raw[0]));
            const float g  = 1.0f / (1.0f + expf(-seas_raw[0]));
            const float ca = 1.0f - a, cg = 1.0f - g;
            float level = __fdividef(xl[0], buf[0]);
            levels[0] = level;
            wsv[S_SEAS] = buf[0];   // ws_full[168] = w_init[0]

            float wq[8], tq[8];
#pragma unroll
            for (int k = 0; k < 8; ++k) {
                const int i = 1 + k;
                const float w = buf[i % S_SEAS];
                wq[k] = w;
                tq[k] = __fdividef(a * xl[i], w);
            }
            for (int i = 1; i < T_LEN; i += 8) {
#pragma unroll
                for (int s = 0; s < 8; ++s) {
                    const int ii = i + s;
                    if (ii >= T_LEN) break;
                    const float w  = wq[s];
                    const float nl = tq[s] + ca * level;   // chain: 1 FMA
                    const float nw = cg * w + __fdividef(g * xl[ii], nl);
                    levels[ii] = nl;
                    buf[ii % S_SEAS] = nw;
                    if (ii + S_SEAS < T_LEN) wsv[ii + S_SEAS] = nw;
                    level = nl;
                    const int i8 = ii + 8;
                    if (i8 < T_LEN) {
                        const float w8 = buf[i8 % S_SEAS];
                        wq[s] = w8;
                        tq[s] = __fdividef(a * xl[i8], w8);
                    }
                }
            }
        }
        return;
    }

    // ------- weight prep: pack MFMA B-frags (m92/m97 layout) -------
    const int idx = (blockIdx.x - 1) * 256 + t;
    auto bfr = [](float f) -> unsigned int {   // fp32 -> bf16 (RNE)
        union { float f; unsigned int u; } v; v.f = f;
        return ((v.u + 0x7FFFu + ((v.u >> 16) & 1u)) >> 16) & 0xFFFFu;
    };
    if (idx < 8192) {                       // pw0: Wh0, 128 frags (8w x 4ns x 4kt)
        const int l = idx & 63, f = idx >> 6;
        const int kt = f & 3, ns = (f >> 2) & 3, w = f >> 4;
        const int g = ns * 128 + w * 16 + (l & 15);
        const int kb = kt * 32 + (l >> 4) * 8;
        const float* s = Wh0 + g * H_SZ + kb;
        uint4 o;
        unsigned int* po = &o.x;
        for (int p = 0; p < 4; ++p) po[p] = bfr(s[2 * p]) | (bfr(s[2 * p + 1]) << 16);
        pw0[idx] = o;
    } else if (idx < 8192 + 16384) {        // pw1: [Wx1 (kt<4); Wh1 (kt>=4)]
        const int j = idx - 8192;
        const int l = j & 63, f = j >> 6;
        const int kt = f & 7, ns = (f >> 3) & 3, w = f >> 5;
        const int g = ns * 128 + w * 16 + (l & 15);
        const float* srcm = (kt < 4) ? Wx1 : Wh1;
        const int kb = (kt & 3) * 32 + (l >> 4) * 8;
        const float* s = srcm + g * H_SZ + kb;
        uint4 o;
        unsigned int* po = &o.x;
        for (int p = 0; p < 4; ++p) po[p] = bfr(s[2 * p]) | (bfr(s[2 * p + 1]) << 16);
        pw1[j] = o;
    } else if (idx < 8192 + 16384 + 16384) {  // tanh_W transpose (fp32)
        const int j = idx - 8192 - 16384;
        const int m = j >> 7, k = j & 127;
        tanhWT[k * H_SZ + m] = tanhW[j];
    }
}

// ---------------------------------------------------------------------------
// Kernel 2: layer-0 LSTM. Wh0 in AGPRs; fused windowing; counted-wait
// barriers (hs0 stores ride across steps, never drained in-loop).
// ---------------------------------------------------------------------------
__global__ __launch_bounds__(512, 2) void l0_kernel(
    const float* __restrict__ x,
    const float* __restrict__ levels,
    const float* __restrict__ wsv,
    const float* __restrict__ noise_in,
    const float* __restrict__ Wx0,
    const float* __restrict__ b0v,
    const uint4* __restrict__ pw0,
    __bf16* __restrict__ hs0) {
    __shared__ __bf16 h0s[2][16 * 128];    // 8KB, swizzled, pitch 256B
    __shared__ float  xls[WIN_SZ][16];     // 10.75KB

    const int tid  = threadIdx.x;
    const int w    = tid >> 6;
    const int lane = tid & 63;
    const int cc   = lane & 15;
    const int kl   = lane >> 4;
    const int base = blockIdx.x * BB;

    // staging: fused window computation (log deseasonalized + noise)
    for (int i = tid; i < WIN_SZ * BB; i += 512) {
        const int t = i >> 4, m = i & 15;
        const int nn = base + m;
        float v = 0.0f;
        if (nn < N_WIN) {
            const float lev = levels[nn + WIN_SZ];
            const int tt = nn + t;
            v = logf(x[tt] / (lev * wsv[tt])) + noise_in[nn * WIN_SZ + t];
        }
        xls[t][m] = v;
    }
    for (int i = tid; i < 2 * 16 * 128; i += 512) (&h0s[0][0])[i] = (__bf16)0.0f;

    // Wh0 frags -> AGPRs (proven round 6)
    const bf16x8* p0 = (const bf16x8*)pw0;
    bf16x8 wB0[4][4];
#pragma unroll
    for (int ns = 0; ns < 4; ++ns)
#pragma unroll
        for (int kt = 0; kt < 4; ++kt)
            wB0[ns][kt] = p0[((w * 4 + ns) * 4 + kt) * 64 + lane];
#pragma unroll
    for (int ns = 0; ns < 4; ++ns)
#pragma unroll
        for (int kt = 0; kt < 4; ++kt)
            asm("" : "+a"(wB0[ns][kt]));

    float b0r[4], wx0r[4];
#pragma unroll
    for (int ns = 0; ns < 4; ++ns) {
        const int g = ns * 128 + w * 16 + cc;
        b0r[ns]  = b0v[g];
        wx0r[ns] = Wx0[g];
    }
    float c0r[4] = {0.f, 0.f, 0.f, 0.f};

    // loop-invariant swizzled LDS addresses (byte offsets)
    int rdA[4], wrA[4], goff[4];
#pragma unroll
    for (int kt = 0; kt < 4; ++kt)
        rdA[kt] = cc * 256 + ((kt * 64 + kl * 16) ^ ((cc & 7) << 4));
#pragma unroll
    for (int r = 0; r < 4; ++r) {
        const int row = kl * 4 + r;
        wrA[r]  = row * 256 + (((w * 16 + cc) * 2) ^ ((row & 7) << 4));
        goff[r] = (base + row) * H_SZ + w * 16 + cc;
    }
    __syncthreads();   // one-time full barrier after init

    char* const hb0 = (char*)&h0s[0][0];

#define L0_STEP(T, P)                                                          \
    {                                                                          \
        const int t_ = (T);                                                    \
        const float4 xt_ = *(const float4*)&xls[t_][kl * 4];                   \
        const float xa_[4] = {xt_.x, xt_.y, xt_.z, xt_.w};                     \
        f32x4 a0_, a1_, a2_, a3_;                                              \
        _Pragma("unroll")                                                      \
        for (int r = 0; r < 4; ++r) {                                          \
            a0_[r] = b0r[0] + wx0r[0] * xa_[r];                                \
            a1_[r] = b0r[1] + wx0r[1] * xa_[r];                                \
            a2_[r] = b0r[2] + wx0r[2] * xa_[r];                                \
            a3_[r] = b0r[3] + wx0r[3] * xa_[r];                                \
        }                                                                      \
        _Pragma("unroll")                                                      \
        for (int kt = 0; kt < 4; ++kt) {                                       \
            const bf16x8 af_ = *(const bf16x8*)(hb0 + (P) * 4096 + rdA[kt]);   \
            a0_ = __builtin_amdgcn_mfma_f32_16x16x32_bf16(af_, wB0[0][kt], a0_, 0, 0, 0); \
            a1_ = __builtin_amdgcn_mfma_f32_16x16x32_bf16(af_, wB0[1][kt], a1_, 0, 0, 0); \
            a2_ = __builtin_amdgcn_mfma_f32_16x16x32_bf16(af_, wB0[2][kt], a2_, 0, 0, 0); \
            a3_ = __builtin_amdgcn_mfma_f32_16x16x32_bf16(af_, wB0[3][kt], a3_, 0, 0, 0); \
        }                                                                      \
        const int off_ = t_ * (NPAD * H_SZ);                                   \
        _Pragma("unroll")                                                      \
        for (int r = 0; r < 4; ++r) {                                          \
            const float ig_ = fsig(a0_[r]);                                    \
            const float fg_ = fsig(a1_[r]);                                    \
            const float gg_ = ftanh(a2_[r]);                                   \
            const float og_ = fsig(a3_[r]);                                    \
            const float c_  = fg_ * c0r[r] + ig_ * gg_;                        \
            c0r[r] = c_;                                                       \
            const __bf16 hb_ = (__bf16)(og_ * ftanh(c_));                      \
            *(__bf16*)(hb0 + (((P) ^ 1) * 4096) + wrA[r]) = hb_;               \
            hs0[off_ + goff[r]] = hb_;   /* store rides across barrier */      \
        }                                                                      \
        LDS_BARRIER();                                                         \
    }

    for (int tp = 0; tp < WIN_SZ / 2; ++tp) {
        L0_STEP(2 * tp, 0)
        L0_STEP(2 * tp + 1, 1)
    }
#undef L0_STEP
}

// ---------------------------------------------------------------------------
// Kernel 3: layer-1 LSTM + head + labels. Wx1+Wh1 in AGPRs; branchless
// 1-step hs0 prefetch into alternating named reg sets; single 8-deep acc
// per gate (round-6 config); counted-wait barriers.
// ---------------------------------------------------------------------------
__global__ __launch_bounds__(512, 2) void l1_kernel(
    const __bf16* __restrict__ hs0,
    const float* __restrict__ b1v,
    const uint4* __restrict__ pw1,
    const float* __restrict__ tanhWT,
    const float* __restrict__ tanhB,
    const float* __restrict__ linW,
    const float* __restrict__ linB,
    const float* __restrict__ x,
    const float* __restrict__ levels,
    const float* __restrict__ wsv,
    const float* __restrict__ noise_lab,
    float* __restrict__ out) {
    __shared__ __bf16 h1s[2][16 * 128];    // 8KB, swizzled
    __shared__ float  hfl[16][129];        // final h (f32) for head
    __shared__ float  featl[16][128];      // tanh features

    const int tid  = threadIdx.x;
    const int w    = tid >> 6;
    const int lane = tid & 63;
    const int cc   = lane & 15;
    const int kl   = lane >> 4;
    const int base = blockIdx.x * BB;

    for (int i = tid; i < 2 * 16 * 128; i += 512) (&h1s[0][0])[i] = (__bf16)0.0f;

    // Wx1 (kt<4) + Wh1 (kt>=4) frags -> AGPRs
    const bf16x8* p1 = (const bf16x8*)pw1;
    bf16x8 wX[4][4], wH[4][4];
#pragma unroll
    for (int ns = 0; ns < 4; ++ns)
#pragma unroll
        for (int kt = 0; kt < 4; ++kt) {
            wX[ns][kt] = p1[((w * 4 + ns) * 8 + kt) * 64 + lane];
            wH[ns][kt] = p1[((w * 4 + ns) * 8 + kt + 4) * 64 + lane];
        }
#pragma unroll
    for (int ns = 0; ns < 4; ++ns)
#pragma unroll
        for (int kt = 0; kt < 4; ++kt) {
            asm("" : "+a"(wX[ns][kt]));
            asm("" : "+a"(wH[ns][kt]));
        }

    float b1r[4];
#pragma unroll
    for (int ns = 0; ns < 4; ++ns) b1r[ns] = b1v[ns * 128 + w * 16 + cc];
    float c1r[4] = {0.f, 0.f, 0.f, 0.f};

    int rdA[4], wrA[4];
#pragma unroll
    for (int kt = 0; kt < 4; ++kt)
        rdA[kt] = cc * 256 + ((kt * 64 + kl * 16) ^ ((cc & 7) << 4));
#pragma unroll
    for (int r = 0; r < 4; ++r) {
        const int row = kl * 4 + r;
        wrA[r] = row * 256 + (((w * 16 + cc) * 2) ^ ((row & 7) << 4));
    }

    // A-frag prefetch for t=0 (set A)
    const size_t arow = (size_t)(base + cc) * H_SZ + kl * 8;
    bf16x8 fA0 = *(const bf16x8*)&hs0[arow + 0];
    bf16x8 fA1 = *(const bf16x8*)&hs0[arow + 32];
    bf16x8 fA2 = *(const bf16x8*)&hs0[arow + 64];
    bf16x8 fA3 = *(const bf16x8*)&hs0[arow + 96];
    bf16x8 fB0, fB1, fB2, fB3;
    __syncthreads();   // one-time full barrier after init

    char* const hb1 = (char*)&h1s[0][0];

#define L1_STEP(T, P, C0, C1, C2, C3, N0, N1, N2, N3)                          \
    {                                                                          \
        const int t_ = (T);                                                    \
        /* branchless prefetch of t+1 (clamped; rides across barrier) */       \
        const int tn_ = (t_ + 1 < WIN_SZ) ? (t_ + 1) : (WIN_SZ - 1);           \
        const __bf16* p_ = hs0 + (size_t)tn_ * (NPAD * H_SZ) + arow;           \
        N0 = *(const bf16x8*)(p_);                                             \
        N1 = *(const bf16x8*)(p_ + 32);                                        \
        N2 = *(const bf16x8*)(p_ + 64);                                        \
        N3 = *(const bf16x8*)(p_ + 96);                                        \
        f32x4 a0_ = {b1r[0], b1r[0], b1r[0], b1r[0]};                          \
        f32x4 a1_ = {b1r[1], b1r[1], b1r[1], b1r[1]};                          \
        f32x4 a2_ = {b1r[2], b1r[2], b1r[2], b1r[2]};                          \
        f32x4 a3_ = {b1r[3], b1r[3], b1r[3], b1r[3]};                          \
        a0_ = __builtin_amdgcn_mfma_f32_16x16x32_bf16(C0, wX[0][0], a0_, 0, 0, 0); \
        a1_ = __builtin_amdgcn_mfma_f32_16x16x32_bf16(C0, wX[1][0], a1_, 0, 0, 0); \
        a2_ = __builtin_amdgcn_mfma_f32_16x16x32_bf16(C0, wX[2][0], a2_, 0, 0, 0); \
        a3_ = __builtin_amdgcn_mfma_f32_16x16x32_bf16(C0, wX[3][0], a3_, 0, 0, 0); \
        a0_ = __builtin_amdgcn_mfma_f32_16x16x32_bf16(C1, wX[0][1], a0_, 0, 0, 0); \
        a1_ = __builtin_amdgcn_mfma_f32_16x16x32_bf16(C1, wX[1][1], a1_, 0, 0, 0); \
        a2_ = __builtin_amdgcn_mfma_f32_16x16x32_bf16(C1, wX[2][1], a2_, 0, 0, 0); \
        a3_ = __builtin_amdgcn_mfma_f32_16x16x32_bf16(C1, wX[3][1], a3_, 0, 0, 0); \
        a0_ = __builtin_amdgcn_mfma_f32_16x16x32_bf16(C2, wX[0][2], a0_, 0, 0, 0); \
        a1_ = __builtin_amdgcn_mfma_f32_16x16x32_bf16(C2, wX[1][2], a1_, 0, 0, 0); \
        a2_ = __builtin_amdgcn_mfma_f32_16x16x32_bf16(C2, wX[2][2], a2_, 0, 0, 0); \
        a3_ = __builtin_amdgcn_mfma_f32_16x16x32_bf16(C2, wX[3][2], a3_, 0, 0, 0); \
        a0_ = __builtin_amdgcn_mfma_f32_16x16x32_bf16(C3, wX[0][3], a0_, 0, 0, 0); \
        a1_ = __builtin_amdgcn_mfma_f32_16x16x32_bf16(C3, wX[1][3], a1_, 0, 0, 0); \
        a2_ = __builtin_amdgcn_mfma_f32_16x16x32_bf16(C3, wX[2][3], a2_, 0, 0, 0); \
        a3_ = __builtin_amdgcn_mfma_f32_16x16x32_bf16(C3, wX[3][3], a3_, 0, 0, 0); \
        _Pragma("unroll")                                                      \
        for (int kt = 0; kt < 4; ++kt) {                                       \
            const bf16x8 af_ = *(const bf16x8*)(hb1 + (P) * 4096 + rdA[kt]);   \
            a0_ = __builtin_amdgcn_mfma_f32_16x16x32_bf16(af_, wH[0][kt], a0_, 0, 0, 0); \
            a1_ = __builtin_amdgcn_mfma_f32_16x16x32_bf16(af_, wH[1][kt], a1_, 0, 0, 0); \
            a2_ = __builtin_amdgcn_mfma_f32_16x16x32_bf16(af_, wH[2][kt], a2_, 0, 0, 0); \
            a3_ = __builtin_amdgcn_mfma_f32_16x16x32_bf16(af_, wH[3][kt], a3_, 0, 0, 0); \
        }                                                                      \
        _Pragma("unroll")                                                      \
        for (int r = 0; r < 4; ++r) {                                          \
            const float ig_ = fsig(a0_[r]);                                    \
            const float fg_ = fsig(a1_[r]);                                    \
            const float gg_ = ftanh(a2_[r]);                                   \
            const float og_ = fsig(a3_[r]);                                    \
            const float c_  = fg_ * c1r[r] + ig_ * gg_;                        \
            c1r[r] = c_;                                                       \
            const float hv_ = og_ * ftanh(c_);                                 \
            if (t_ == WIN_SZ - 1) {                                            \
                hfl[kl * 4 + r][w * 16 + cc] = hv_;                            \
            } else {                                                           \
                *(__bf16*)(hb1 + (((P) ^ 1) * 4096) + wrA[r]) = (__bf16)hv_;   \
            }                                                                  \
        }                                                                      \
        LDS_BARRIER();                                                         \
    }

    for (int tp = 0; tp < WIN_SZ / 2; ++tp) {
        L1_STEP(2 * tp, 0, fA0, fA1, fA2, fA3, fB0, fB1, fB2, fB3)
        L1_STEP(2 * tp + 1, 1, fB0, fB1, fB2, fB3, fA0, fA1, fA2, fA3)
    }
#undef L1_STEP

    // ---- epilogue: feat = tanh(h @ tanhW^T + tanhB) (block-local) ----
    for (int p = tid; p < BB * H_SZ; p += 512) {
        const int m = p >> 7, u = p & 127;
        float acc = tanhB[u];
        for (int k = 0; k < H_SZ; ++k)
            acc += hfl[m][k] * tanhWT[k * H_SZ + u];
        featl[m][u] = tanhf(acc);
    }
    LDS_BARRIER();

    // ---- out = feat @ linW^T + linB; labels; loss scalar ----
    for (int p = tid; p < BB * OUT_SZ; p += 512) {
        const int m = p / OUT_SZ, o = p % OUT_SZ;
        const int nn = base + m;
        if (nn < N_WIN) {
            float acc = linB[o];
            for (int k = 0; k < H_SZ; ++k)
                acc += featl[m][k] * linW[o * H_SZ + k];
            out[nn * OUT_SZ + o] = acc;
            const float lev = levels[nn + WIN_SZ];
            const int tt = nn + WIN_SZ + o;
            out[N_WIN * OUT_SZ + nn * OUT_SZ + o] =
                logf(x[tt] / (lev * wsv[tt])) + noise_lab[nn * OUT_SZ + o];
        }
    }
    if (blockIdx.x == 0 && tid == 0)
        out[2 * N_WIN * OUT_SZ] = 0.0f;   // level_var_loss
}

// ---------------------------------------------------------------------------
extern "C" void kernel_launch(void* const* d_in, const int* in_sizes, int n_in,
                              void* d_out, int out_size, void* d_ws, size_t ws_size,
                              hipStream_t stream) {
    const float* x           = (const float*)d_in[0];
    const float* lvl_raw     = (const float*)d_in[1];
    const float* seas_raw    = (const float*)d_in[2];
    const float* seas_params = (const float*)d_in[3];
    const float* noise_in    = (const float*)d_in[4];
    const float* noise_lab   = (const float*)d_in[5];
    const float* Wx0         = (const float*)d_in[6];
    const float* Wh0         = (const float*)d_in[7];
    const float* b0v         = (const float*)d_in[8];
    const float* Wx1         = (const float*)d_in[9];
    const float* Wh1         = (const float*)d_in[10];
    const float* b1v         = (const float*)d_in[11];
    const float* tanhW       = (const float*)d_in[12];
    const float* tanhB       = (const float*)d_in[13];
    const float* linW        = (const float*)d_in[14];
    const float* linB        = (const float*)d_in[15];
    float* out = (float*)d_out;

    // workspace layout (floats; pw0/pw1/hs0 16B-aligned by construction)
    float* wsf    = (float*)d_ws;
    float* levels = wsf;                                   // 1024
    float* wsv    = levels + T_LEN;                        // 1024
    float* tanhWT = wsv + T_LEN;                           // 16384
    uint4* pw0    = (uint4*)(tanhWT + H_SZ * H_SZ);        // 8192 uint4
    uint4* pw1    = pw0 + 8192;                            // 16384 uint4
    __bf16* hs0   = (__bf16*)(pw1 + 16384);                // 168*848*128 bf16

    hipLaunchKernelGGL(pre_kernel, dim3(161), dim3(256), 0, stream,
                       x, lvl_raw, seas_raw, seas_params, Wh0, Wx1, Wh1, tanhW,
                       levels, wsv, pw0, pw1, tanhWT);
    hipLaunchKernelGGL(l0_kernel, dim3(NBLK), dim3(512), 0, stream,
                       x, levels, wsv, noise_in, Wx0, b0v, pw0, hs0);
    hipLaunchKernelGGL(l1_kernel, dim3(NBLK), dim3(512), 0, stream,
                       hs0, b1v, pw1, tanhWT, tanhB, linW, linB,
                       x, levels, wsv, noise_lab, out);
}